// Round 3
// baseline (56.993 us; speedup 1.0000x reference)
//
#include <hip/hip_runtime.h>
#include <hip/hip_bf16.h>
#include <math.h>

// Problem constants (from reference): N=8 clouds, P=4096 points, D=3
constexpr int NB  = 8;
constexpr int PP  = 4096;

// Kernel A tiling
constexpr int TPB = 256;          // threads per block
constexpr int XPT = 8;            // x points per thread
constexpr int XCH = TPB * XPT;    // 2048 x points per block
constexpr int NXC = PP / XCH;     // 2 x chunks
constexpr int NYC = 32;           // y chunks
constexpr int YCH = PP / NYC;     // 128 y points per chunk
constexpr int GRIDA = 2 * NB * NXC * NYC;   // 1024 blocks

// Kernel B segmentation
constexpr int NSEG = 4;           // segments per (dir, cloud)
constexpr int SEGP = PP / NSEG;   // 1024 x points per segment
constexpr int NPART = 2 * NB * NSEG;  // 64 partials

// ---------------------------------------------------------------------------
// Kernel A: per (dir, cloud, x-chunk, y-chunk): partial min-d2 over the
// y-chunk for 2048 x points. y staged in LDS as (-2y0,-2y1,-2y2,|y|^2) so
// the inner op is 3 FMA (+ shared min3 per 2 pairs). Per-wave contiguous
// x layout allows whole-wave skip of padded query rows. Work item id is
// scrambled (*331 mod 1024) so co-resident blocks get decorrelated yc ->
// uniform per-CU work. Also zeroes kernel B's completion counter.
// ---------------------------------------------------------------------------
__global__ __launch_bounds__(TPB, 4) void nn_partial(
    const float* __restrict__ x, const float* __restrict__ y,
    const int* __restrict__ xlen, const int* __restrict__ ylen,
    float* __restrict__ ws, unsigned int* __restrict__ counter)
{
    __shared__ float4 sy[YCH];

    if (blockIdx.x == 0 && threadIdx.x == 0) atomicExch(counter, 0u);

    const int item = ((int)blockIdx.x * 331) & (GRIDA - 1);   // bijective scramble
    const int yc  = item & (NYC - 1);
    const int xc  = (item >> 5) & (NXC - 1);
    const int n   = (item >> 6) & (NB - 1);
    const int dir = (item >> 9) & 1;

    const float* __restrict__ xs = dir ? y : x;    // query set
    const float* __restrict__ ys = dir ? x : y;    // search set
    const int yl = (dir ? xlen : ylen)[n];         // valid points in search set
    const int ql = (dir ? ylen : xlen)[n];         // valid points in query set

    // ---- stage y-chunk into LDS as (-2y0, -2y1, -2y2, |y|^2) ----
    const float* __restrict__ yb = ys + ((size_t)n * PP + (size_t)yc * YCH) * 3;
    if ((int)threadIdx.x < YCH) {
        const int p = (int)threadIdx.x;
        float y0 = yb[p * 3 + 0];
        float y1 = yb[p * 3 + 1];
        float y2 = yb[p * 3 + 2];
        sy[p] = make_float4(-2.f * y0, -2.f * y1, -2.f * y2,
                            fmaf(y0, y0, fmaf(y1, y1, y2 * y2)));
    }

    // ---- load XPT x points, wave-contiguous: xi = wbase + k*64 + lane ----
    const int wave  = (int)threadIdx.x >> 6;
    const int lane  = (int)threadIdx.x & 63;
    const int wbase = xc * XCH + wave * (XPT * 64);   // 512 x points per wave

    float px0[XPT], px1[XPT], px2[XPT], a[XPT], emin[XPT];
    const float* __restrict__ xb = xs + (size_t)n * PP * 3;
#pragma unroll
    for (int k = 0; k < XPT; ++k) {
        const int xi = wbase + k * 64 + lane;
        px0[k] = xb[xi * 3 + 0];
        px1[k] = xb[xi * 3 + 1];
        px2[k] = xb[xi * 3 + 2];
        a[k]   = fmaf(px0[k], px0[k], fmaf(px1[k], px1[k], px2[k] * px2[k]));
        emin[k] = INFINITY;
    }
    __syncthreads();

    int jend = yl - yc * YCH;
    if (jend > YCH) jend = YCH;           // may be <= 0 (empty chunk)

    // whole-wave skip when every query row this wave owns is padding
    if (ql > wbase && jend > 0) {
        const int j2 = jend & ~1;
#pragma unroll 2
        for (int j = 0; j < j2; j += 2) {
            const float4 u = sy[j];
            const float4 v = sy[j + 1];
#pragma unroll
            for (int k = 0; k < XPT; ++k) {
                float e1 = fmaf(px0[k], u.x, fmaf(px1[k], u.y, fmaf(px2[k], u.z, u.w)));
                float e2 = fmaf(px0[k], v.x, fmaf(px1[k], v.y, fmaf(px2[k], v.z, v.w)));
                emin[k] = fminf(emin[k], fminf(e1, e2));   // -> v_min3_f32
            }
        }
        if (jend & 1) {
            const float4 u = sy[jend - 1];
#pragma unroll
            for (int k = 0; k < XPT; ++k) {
                float e1 = fmaf(px0[k], u.x, fmaf(px1[k], u.y, fmaf(px2[k], u.z, u.w)));
                emin[k] = fminf(emin[k], e1);
            }
        }
    }

    float* __restrict__ w = ws + ((size_t)(dir * NB + n) * NYC + yc) * PP;
#pragma unroll
    for (int k = 0; k < XPT; ++k) {
        w[wbase + k * 64 + lane] = a[k] + emin[k];   // inf for skipped waves
    }
}

// ---------------------------------------------------------------------------
// Kernel B: per (dir, cloud, segment): min over y-chunks, mask padded x,
// sum, divide by max(len,1)*NB, write partial. Last block (device-scope
// counter) sums the 64 partials in fixed order -> scalar out. Deterministic.
// ---------------------------------------------------------------------------
__global__ __launch_bounds__(256) void reduce_cloud(
    const float* __restrict__ ws,
    const int* __restrict__ xlen, const int* __restrict__ ylen,
    float* __restrict__ partial, unsigned int* __restrict__ counter,
    float* __restrict__ out)
{
    const int b   = blockIdx.x;          // 0..63
    const int seg = b & (NSEG - 1);
    const int c   = b >> 2;              // 0..15
    const int dir = c >> 3;
    const int n   = c & (NB - 1);
    const int xl  = (dir ? ylen : xlen)[n];   // valid query points

    const float* __restrict__ w = ws + (size_t)c * NYC * PP;
    float sum = 0.f;
    const int i0 = seg * SEGP;
    for (int i = i0 + (int)threadIdx.x; i < i0 + SEGP; i += 256) {
        float m = w[i];
#pragma unroll
        for (int ch = 1; ch < NYC; ++ch) m = fminf(m, w[(size_t)ch * PP + i]);
        if (i < xl) sum += m;
    }

    // block reduction (4 waves of 64)
#pragma unroll
    for (int off = 32; off > 0; off >>= 1) sum += __shfl_xor(sum, off);
    __shared__ float ls[4];
    const int lane = (int)threadIdx.x & 63;
    const int wv   = (int)threadIdx.x >> 6;
    if (lane == 0) ls[wv] = sum;
    __syncthreads();
    if (threadIdx.x == 0) {
        float tot = ls[0] + ls[1] + ls[2] + ls[3];
        int d = xl > 1 ? xl : 1;
        partial[b] = tot / (float)d / (float)NB;
        __threadfence();                               // release partial
        unsigned int old = atomicAdd(counter, 1u);     // device-scope
        if (old == NPART - 1) {
            __threadfence();                           // acquire
            float s = 0.f;
            for (int i = 0; i < NPART; ++i)
                s += atomicAdd(&partial[i], 0.0f);     // coherent read, fixed order
            out[0] = s;
        }
    }
}

// ---------------------------------------------------------------------------
// Fallback (ws too small): no y-split; LDS multi-pass over y chunks; block
// sum + atomicAdd of the pre-divided contribution. Needs d_out zeroed first.
// ---------------------------------------------------------------------------
__global__ __launch_bounds__(TPB) void chamfer_atomic(
    const float* __restrict__ x, const float* __restrict__ y,
    const int* __restrict__ xlen, const int* __restrict__ ylen,
    float* __restrict__ out)
{
    __shared__ float4 sy[YCH];

    int bid = blockIdx.x;
    const int xc  = bid & (NXC - 1); bid >>= 1;
    const int n   = bid & (NB - 1);  bid >>= 3;
    const int dir = bid;

    const float* __restrict__ xs = dir ? y : x;
    const float* __restrict__ ys = dir ? x : y;
    const int yl = (dir ? xlen : ylen)[n];
    const int xl = (dir ? ylen : xlen)[n];

    float m0[XPT], m1[XPT], m2[XPT], a[XPT], emin[XPT];
    const int xi0 = xc * XCH + (int)threadIdx.x;
    const float* __restrict__ xb = xs + (size_t)n * PP * 3;
#pragma unroll
    for (int k = 0; k < XPT; ++k) {
        int xi = xi0 + k * TPB;
        float x0 = xb[xi * 3 + 0];
        float x1 = xb[xi * 3 + 1];
        float x2 = xb[xi * 3 + 2];
        m0[k] = -2.f * x0; m1[k] = -2.f * x1; m2[k] = -2.f * x2;
        a[k]  = fmaf(x0, x0, fmaf(x1, x1, x2 * x2));
        emin[k] = INFINITY;
    }

    for (int yc = 0; yc < NYC; ++yc) {
        const float* __restrict__ ybase = ys + ((size_t)n * PP + (size_t)yc * YCH) * 3;
        __syncthreads();
        if ((int)threadIdx.x < YCH) {
            int p = (int)threadIdx.x;
            float y0 = ybase[p * 3 + 0];
            float y1 = ybase[p * 3 + 1];
            float y2 = ybase[p * 3 + 2];
            sy[p] = make_float4(y0, y1, y2, fmaf(y0, y0, fmaf(y1, y1, y2 * y2)));
        }
        __syncthreads();
        int jend = yl - yc * YCH;
        if (jend > YCH) jend = YCH;
#pragma unroll 4
        for (int j = 0; j < jend; ++j) {
            float4 v = sy[j];
#pragma unroll
            for (int k = 0; k < XPT; ++k) {
                float e = fmaf(m0[k], v.x, fmaf(m1[k], v.y, fmaf(m2[k], v.z, v.w)));
                emin[k] = fminf(emin[k], e);
            }
        }
    }

    float sum = 0.f;
#pragma unroll
    for (int k = 0; k < XPT; ++k) {
        int xi = xi0 + k * TPB;
        if (xi < xl) sum += a[k] + emin[k];
    }
#pragma unroll
    for (int off = 32; off > 0; off >>= 1) sum += __shfl_xor(sum, off);
    __shared__ float ls[4];
    const int lane = (int)threadIdx.x & 63;
    const int wv   = (int)threadIdx.x >> 6;
    if (lane == 0) ls[wv] = sum;
    __syncthreads();
    if (threadIdx.x == 0) {
        float tot = ls[0] + ls[1] + ls[2] + ls[3];
        int d = xl > 1 ? xl : 1;
        atomicAdd(out, tot / (float)d / (float)NB);
    }
}

extern "C" void kernel_launch(void* const* d_in, const int* in_sizes, int n_in,
                              void* d_out, int out_size, void* d_ws, size_t ws_size,
                              hipStream_t stream) {
    const float* x  = (const float*)d_in[0];
    const float* y  = (const float*)d_in[1];
    const int* xl   = (const int*)d_in[2];
    const int* yl   = (const int*)d_in[3];
    float* out      = (float*)d_out;

    const size_t ws_floats = (size_t)2 * NB * NYC * PP;                 // partial d2 table
    const size_t ws_need   = (ws_floats + NPART + 1) * sizeof(float);   // + partials + counter

    if (ws_size >= ws_need) {
        float* ws            = (float*)d_ws;
        float* partial       = ws + ws_floats;
        unsigned int* counter = (unsigned int*)(partial + NPART);
        nn_partial<<<GRIDA, TPB, 0, stream>>>(x, y, xl, yl, ws, counter);
        reduce_cloud<<<NPART, 256, 0, stream>>>(ws, xl, yl, partial, counter, out);
    } else {
        hipMemsetAsync(d_out, 0, sizeof(float), stream);
        const int gridF = 2 * NB * NXC;         // 32 blocks
        chamfer_atomic<<<gridF, TPB, 0, stream>>>(x, y, xl, yl, out);
    }
}

// Round 4
// 35.181 us; speedup vs baseline: 1.6200x; 1.6200x over previous
//
#include <hip/hip_runtime.h>
#include <hip/hip_bf16.h>
#include <math.h>

// Problem constants (from reference): N=8 clouds, P=4096 points, D=3
constexpr int NB  = 8;
constexpr int PP  = 4096;

// Kernel A tiling
constexpr int TPB = 256;          // threads per block
constexpr int XPT = 8;            // x points per thread
constexpr int XCH = TPB * XPT;    // 2048 x points per block
constexpr int NXC = PP / XCH;     // 2 x chunks
constexpr int NYC = 32;           // y chunks
constexpr int YCH = PP / NYC;     // 128 y points per chunk
constexpr int GRIDA = 2 * NB * NXC * NYC;   // 1024 blocks

// Kernel B segmentation
constexpr int NSEG = 4;           // segments per (dir, cloud)
constexpr int SEGP = PP / NSEG;   // 1024 x points per segment
constexpr int NPART = 2 * NB * NSEG;  // 64 partials

// ---------------------------------------------------------------------------
// Kernel A: per (dir, cloud, x-chunk, y-chunk): partial min-d2 over the
// y-chunk for 2048 x points. y staged in LDS as (-2y0,-2y1,-2y2,|y|^2) so
// the inner op is 3 FMA (+ min3 shared over 2 pairs -> 3.5 ops/pair).
// Per-wave contiguous x layout allows whole-wave skip of padded query rows.
// Work item id is scrambled (*331 mod 1024) so co-resident blocks get
// decorrelated yc -> uniform per-CU work.
// ---------------------------------------------------------------------------
__global__ __launch_bounds__(TPB, 4) void nn_partial(
    const float* __restrict__ x, const float* __restrict__ y,
    const int* __restrict__ xlen, const int* __restrict__ ylen,
    float* __restrict__ ws)
{
    __shared__ float4 sy[YCH];

    const int item = ((int)blockIdx.x * 331) & (GRIDA - 1);   // bijective scramble
    const int yc  = item & (NYC - 1);
    const int xc  = (item >> 5) & (NXC - 1);
    const int n   = (item >> 6) & (NB - 1);
    const int dir = (item >> 9) & 1;

    const float* __restrict__ xs = dir ? y : x;    // query set
    const float* __restrict__ ys = dir ? x : y;    // search set
    const int yl = (dir ? xlen : ylen)[n];         // valid points in search set
    const int ql = (dir ? ylen : xlen)[n];         // valid points in query set

    // ---- stage y-chunk into LDS as (-2y0, -2y1, -2y2, |y|^2) ----
    const float* __restrict__ yb = ys + ((size_t)n * PP + (size_t)yc * YCH) * 3;
    if ((int)threadIdx.x < YCH) {
        const int p = (int)threadIdx.x;
        float y0 = yb[p * 3 + 0];
        float y1 = yb[p * 3 + 1];
        float y2 = yb[p * 3 + 2];
        sy[p] = make_float4(-2.f * y0, -2.f * y1, -2.f * y2,
                            fmaf(y0, y0, fmaf(y1, y1, y2 * y2)));
    }

    // ---- load XPT x points, wave-contiguous: xi = wbase + k*64 + lane ----
    const int wave  = (int)threadIdx.x >> 6;
    const int lane  = (int)threadIdx.x & 63;
    const int wbase = xc * XCH + wave * (XPT * 64);   // 512 x points per wave

    float px0[XPT], px1[XPT], px2[XPT], a[XPT], emin[XPT];
    const float* __restrict__ xb = xs + (size_t)n * PP * 3;
#pragma unroll
    for (int k = 0; k < XPT; ++k) {
        const int xi = wbase + k * 64 + lane;
        px0[k] = xb[xi * 3 + 0];
        px1[k] = xb[xi * 3 + 1];
        px2[k] = xb[xi * 3 + 2];
        a[k]   = fmaf(px0[k], px0[k], fmaf(px1[k], px1[k], px2[k] * px2[k]));
        emin[k] = INFINITY;
    }
    __syncthreads();

    int jend = yl - yc * YCH;
    if (jend > YCH) jend = YCH;           // may be <= 0 (empty chunk)

    // whole-wave skip when every query row this wave owns is padding
    if (ql > wbase && jend > 0) {
        const int j2 = jend & ~1;
#pragma unroll 2
        for (int j = 0; j < j2; j += 2) {
            const float4 u = sy[j];
            const float4 v = sy[j + 1];
#pragma unroll
            for (int k = 0; k < XPT; ++k) {
                float e1 = fmaf(px0[k], u.x, fmaf(px1[k], u.y, fmaf(px2[k], u.z, u.w)));
                float e2 = fmaf(px0[k], v.x, fmaf(px1[k], v.y, fmaf(px2[k], v.z, v.w)));
                emin[k] = fminf(emin[k], fminf(e1, e2));   // -> v_min3_f32
            }
        }
        if (jend & 1) {
            const float4 u = sy[jend - 1];
#pragma unroll
            for (int k = 0; k < XPT; ++k) {
                float e1 = fmaf(px0[k], u.x, fmaf(px1[k], u.y, fmaf(px2[k], u.z, u.w)));
                emin[k] = fminf(emin[k], e1);
            }
        }
    }

    float* __restrict__ w = ws + ((size_t)(dir * NB + n) * NYC + yc) * PP;
#pragma unroll
    for (int k = 0; k < XPT; ++k) {
        w[wbase + k * 64 + lane] = a[k] + emin[k];   // inf for skipped waves
    }
}

// ---------------------------------------------------------------------------
// Kernel B: per (dir, cloud, segment): min over y-chunks, mask padded x,
// sum, divide by max(len,1)*NB, write partial. 64 blocks. Deterministic.
// ---------------------------------------------------------------------------
__global__ __launch_bounds__(256) void reduce_cloud(
    const float* __restrict__ ws,
    const int* __restrict__ xlen, const int* __restrict__ ylen,
    float* __restrict__ partial)
{
    const int b   = blockIdx.x;          // 0..63
    const int seg = b & (NSEG - 1);
    const int c   = b >> 2;              // 0..15
    const int dir = c >> 3;
    const int n   = c & (NB - 1);
    const int xl  = (dir ? ylen : xlen)[n];   // valid query points

    const float* __restrict__ w = ws + (size_t)c * NYC * PP;
    float sum = 0.f;
    const int i0 = seg * SEGP;
    for (int i = i0 + (int)threadIdx.x; i < i0 + SEGP; i += 256) {
        float m = w[i];
#pragma unroll
        for (int ch = 1; ch < NYC; ++ch) m = fminf(m, w[(size_t)ch * PP + i]);
        if (i < xl) sum += m;
    }

    // block reduction (4 waves of 64)
#pragma unroll
    for (int off = 32; off > 0; off >>= 1) sum += __shfl_xor(sum, off);
    __shared__ float ls[4];
    const int lane = (int)threadIdx.x & 63;
    const int wv   = (int)threadIdx.x >> 6;
    if (lane == 0) ls[wv] = sum;
    __syncthreads();
    if (threadIdx.x == 0) {
        float tot = ls[0] + ls[1] + ls[2] + ls[3];
        int d = xl > 1 ? xl : 1;
        partial[b] = tot / (float)d / (float)NB;
    }
}

// ---------------------------------------------------------------------------
// Kernel C: sum the 64 partials -> scalar output. Deterministic.
// ---------------------------------------------------------------------------
__global__ __launch_bounds__(64) void final_sum(
    const float* __restrict__ partial, float* __restrict__ out)
{
    float v = partial[threadIdx.x];
#pragma unroll
    for (int off = 32; off > 0; off >>= 1) v += __shfl_xor(v, off);
    if (threadIdx.x == 0) out[0] = v;
}

// ---------------------------------------------------------------------------
// Fallback (ws too small): no y-split; LDS multi-pass over y chunks; block
// sum + atomicAdd of the pre-divided contribution. Needs d_out zeroed first.
// ---------------------------------------------------------------------------
__global__ __launch_bounds__(TPB) void chamfer_atomic(
    const float* __restrict__ x, const float* __restrict__ y,
    const int* __restrict__ xlen, const int* __restrict__ ylen,
    float* __restrict__ out)
{
    __shared__ float4 sy[YCH];

    int bid = blockIdx.x;
    const int xc  = bid & (NXC - 1); bid >>= 1;
    const int n   = bid & (NB - 1);  bid >>= 3;
    const int dir = bid;

    const float* __restrict__ xs = dir ? y : x;
    const float* __restrict__ ys = dir ? x : y;
    const int yl = (dir ? xlen : ylen)[n];
    const int xl = (dir ? ylen : xlen)[n];

    float m0[XPT], m1[XPT], m2[XPT], a[XPT], emin[XPT];
    const int xi0 = xc * XCH + (int)threadIdx.x;
    const float* __restrict__ xb = xs + (size_t)n * PP * 3;
#pragma unroll
    for (int k = 0; k < XPT; ++k) {
        int xi = xi0 + k * TPB;
        float x0 = xb[xi * 3 + 0];
        float x1 = xb[xi * 3 + 1];
        float x2 = xb[xi * 3 + 2];
        m0[k] = -2.f * x0; m1[k] = -2.f * x1; m2[k] = -2.f * x2;
        a[k]  = fmaf(x0, x0, fmaf(x1, x1, x2 * x2));
        emin[k] = INFINITY;
    }

    for (int yc = 0; yc < NYC; ++yc) {
        const float* __restrict__ ybase = ys + ((size_t)n * PP + (size_t)yc * YCH) * 3;
        __syncthreads();
        if ((int)threadIdx.x < YCH) {
            int p = (int)threadIdx.x;
            float y0 = ybase[p * 3 + 0];
            float y1 = ybase[p * 3 + 1];
            float y2 = ybase[p * 3 + 2];
            sy[p] = make_float4(y0, y1, y2, fmaf(y0, y0, fmaf(y1, y1, y2 * y2)));
        }
        __syncthreads();
        int jend = yl - yc * YCH;
        if (jend > YCH) jend = YCH;
#pragma unroll 4
        for (int j = 0; j < jend; ++j) {
            float4 v = sy[j];
#pragma unroll
            for (int k = 0; k < XPT; ++k) {
                float e = fmaf(m0[k], v.x, fmaf(m1[k], v.y, fmaf(m2[k], v.z, v.w)));
                emin[k] = fminf(emin[k], e);
            }
        }
    }

    float sum = 0.f;
#pragma unroll
    for (int k = 0; k < XPT; ++k) {
        int xi = xi0 + k * TPB;
        if (xi < xl) sum += a[k] + emin[k];
    }
#pragma unroll
    for (int off = 32; off > 0; off >>= 1) sum += __shfl_xor(sum, off);
    __shared__ float ls[4];
    const int lane = (int)threadIdx.x & 63;
    const int wv   = (int)threadIdx.x >> 6;
    if (lane == 0) ls[wv] = sum;
    __syncthreads();
    if (threadIdx.x == 0) {
        float tot = ls[0] + ls[1] + ls[2] + ls[3];
        int d = xl > 1 ? xl : 1;
        atomicAdd(out, tot / (float)d / (float)NB);
    }
}

extern "C" void kernel_launch(void* const* d_in, const int* in_sizes, int n_in,
                              void* d_out, int out_size, void* d_ws, size_t ws_size,
                              hipStream_t stream) {
    const float* x  = (const float*)d_in[0];
    const float* y  = (const float*)d_in[1];
    const int* xl   = (const int*)d_in[2];
    const int* yl   = (const int*)d_in[3];
    float* out      = (float*)d_out;

    const size_t ws_floats = (size_t)2 * NB * NYC * PP;             // partial d2 table
    const size_t ws_need   = (ws_floats + NPART) * sizeof(float);   // + partials

    if (ws_size >= ws_need) {
        float* ws      = (float*)d_ws;
        float* partial = ws + ws_floats;
        nn_partial<<<GRIDA, TPB, 0, stream>>>(x, y, xl, yl, ws);
        reduce_cloud<<<NPART, 256, 0, stream>>>(ws, xl, yl, partial);
        final_sum<<<1, 64, 0, stream>>>(partial, out);
    } else {
        hipMemsetAsync(d_out, 0, sizeof(float), stream);
        const int gridF = 2 * NB * NXC;         // 32 blocks
        chamfer_atomic<<<gridF, TPB, 0, stream>>>(x, y, xl, yl, out);
    }
}

// Round 5
// 27.549 us; speedup vs baseline: 2.0688x; 1.2770x over previous
//
#include <hip/hip_runtime.h>
#include <hip/hip_bf16.h>
#include <math.h>

// Problem constants (from reference): N=8 clouds, P=4096 points, D=3
constexpr int NB  = 8;
constexpr int PP  = 4096;

// Kernel A tiling
constexpr int TPB = 256;          // threads per block
constexpr int XPT = 4;            // x points per thread
constexpr int XCH = TPB * XPT;    // 1024 x points per block
constexpr int NXC = PP / XCH;     // 4 x chunks
constexpr int NYC = 32;           // strided y slices (stride = NYC)
constexpr int YCH = PP / NYC;     // 128 y points per slice
constexpr int GRIDA = 2 * NB * NXC * NYC;   // 2048 blocks (2x oversubscribed)

// Kernel B segmentation
constexpr int NSEG = 16;              // segments per (dir, cloud)
constexpr int SEGP = PP / NSEG;       // 256 x points per segment
constexpr int NPART = 2 * NB * NSEG;  // 256 partials

// ---------------------------------------------------------------------------
// Kernel A: per (dir, cloud, x-chunk, y-slice): partial min-d2 over the
// STRIDED y-slice {yc + 32*t} for 1024 x points. Strided slices give every
// block of a cloud an identical trip count (jend = ceil((yl-yc)/32)) ->
// uniform block duration; 2x grid oversubscription (1024 resident + 1024
// queued at 4 blocks/CU) lets the CP backfill freed slots -> balanced tail.
// y staged in LDS as (-2y0,-2y1,-2y2,|y|^2): 3 FMA + min3/2pairs = 3.5
// ops/pair. Whole-wave skip when all 256 owned query rows are padding.
// ---------------------------------------------------------------------------
__global__ __launch_bounds__(TPB, 4) void nn_partial(
    const float* __restrict__ x, const float* __restrict__ y,
    const int* __restrict__ xlen, const int* __restrict__ ylen,
    float* __restrict__ ws)
{
    __shared__ float4 sy[YCH];

    const int bid = (int)blockIdx.x;
    const int yc  = bid & (NYC - 1);
    const int xc  = (bid >> 5) & (NXC - 1);
    const int n   = (bid >> 7) & (NB - 1);
    const int dir = bid >> 10;

    const float* __restrict__ xs = dir ? y : x;    // query set
    const float* __restrict__ ys = dir ? x : y;    // search set
    const int yl = (dir ? xlen : ylen)[n];         // valid points in search set
    const int ql = (dir ? ylen : xlen)[n];         // valid points in query set

    // ---- stage strided y-slice into LDS as (-2y0, -2y1, -2y2, |y|^2) ----
    const float* __restrict__ yb = ys + (size_t)n * PP * 3;
    if ((int)threadIdx.x < YCH) {
        const int p   = (int)threadIdx.x;
        const int idx = yc + NYC * p;              // < PP always
        float y0 = yb[idx * 3 + 0];
        float y1 = yb[idx * 3 + 1];
        float y2 = yb[idx * 3 + 2];
        sy[p] = make_float4(-2.f * y0, -2.f * y1, -2.f * y2,
                            fmaf(y0, y0, fmaf(y1, y1, y2 * y2)));
    }

    // ---- load XPT x points, wave-contiguous: xi = wbase + k*64 + lane ----
    const int wave  = (int)threadIdx.x >> 6;
    const int lane  = (int)threadIdx.x & 63;
    const int wbase = xc * XCH + wave * (XPT * 64);   // 256 x points per wave

    float px0[XPT], px1[XPT], px2[XPT], a[XPT], emin[XPT];
    const float* __restrict__ xb = xs + (size_t)n * PP * 3;
#pragma unroll
    for (int k = 0; k < XPT; ++k) {
        const int xi = wbase + k * 64 + lane;
        px0[k] = xb[xi * 3 + 0];
        px1[k] = xb[xi * 3 + 1];
        px2[k] = xb[xi * 3 + 2];
        a[k]   = fmaf(px0[k], px0[k], fmaf(px1[k], px1[k], px2[k] * px2[k]));
        emin[k] = INFINITY;
    }
    __syncthreads();

    // trip count: number of valid points in this strided slice
    int jend = (yl - yc + NYC - 1) >> 5;   // ceil((yl-yc)/32), yl >= yc+1 here
    if (jend > YCH) jend = YCH;

    // whole-wave skip when every query row this wave owns is padding
    if (ql > wbase && jend > 0) {
        const int j2 = jend & ~1;
#pragma unroll 2
        for (int j = 0; j < j2; j += 2) {
            const float4 u = sy[j];
            const float4 v = sy[j + 1];
#pragma unroll
            for (int k = 0; k < XPT; ++k) {
                float e1 = fmaf(px0[k], u.x, fmaf(px1[k], u.y, fmaf(px2[k], u.z, u.w)));
                float e2 = fmaf(px0[k], v.x, fmaf(px1[k], v.y, fmaf(px2[k], v.z, v.w)));
                emin[k] = fminf(emin[k], fminf(e1, e2));   // -> v_min3_f32
            }
        }
        if (jend & 1) {
            const float4 u = sy[jend - 1];
#pragma unroll
            for (int k = 0; k < XPT; ++k) {
                float e1 = fmaf(px0[k], u.x, fmaf(px1[k], u.y, fmaf(px2[k], u.z, u.w)));
                emin[k] = fminf(emin[k], e1);
            }
        }
    }

    float* __restrict__ w = ws + ((size_t)(dir * NB + n) * NYC + yc) * PP;
#pragma unroll
    for (int k = 0; k < XPT; ++k) {
        w[wbase + k * 64 + lane] = a[k] + emin[k];   // inf for skipped waves
    }
}

// ---------------------------------------------------------------------------
// Kernel B: per (dir, cloud, segment): min over the 32 y-slices, mask padded
// x, sum, divide by max(len,1)*NB, write partial. 256 blocks, one element
// per thread, 32-deep MLP. Deterministic.
// ---------------------------------------------------------------------------
__global__ __launch_bounds__(256) void reduce_cloud(
    const float* __restrict__ ws,
    const int* __restrict__ xlen, const int* __restrict__ ylen,
    float* __restrict__ partial)
{
    const int b   = blockIdx.x;          // 0..255
    const int seg = b & (NSEG - 1);
    const int c   = b >> 4;              // 0..15
    const int dir = c >> 3;
    const int n   = c & (NB - 1);
    const int xl  = (dir ? ylen : xlen)[n];   // valid query points

    const float* __restrict__ w = ws + (size_t)c * NYC * PP;
    const int i = seg * SEGP + (int)threadIdx.x;

    float m = w[i];
#pragma unroll
    for (int ch = 1; ch < NYC; ++ch) m = fminf(m, w[(size_t)ch * PP + i]);
    float sum = (i < xl) ? m : 0.f;

    // block reduction (4 waves of 64)
#pragma unroll
    for (int off = 32; off > 0; off >>= 1) sum += __shfl_xor(sum, off);
    __shared__ float ls[4];
    const int lane = (int)threadIdx.x & 63;
    const int wv   = (int)threadIdx.x >> 6;
    if (lane == 0) ls[wv] = sum;
    __syncthreads();
    if (threadIdx.x == 0) {
        float tot = ls[0] + ls[1] + ls[2] + ls[3];
        int d = xl > 1 ? xl : 1;
        partial[b] = tot / (float)d / (float)NB;
    }
}

// ---------------------------------------------------------------------------
// Kernel C: sum the 256 partials -> scalar output. Deterministic.
// ---------------------------------------------------------------------------
__global__ __launch_bounds__(256) void final_sum(
    const float* __restrict__ partial, float* __restrict__ out)
{
    float v = partial[threadIdx.x];
#pragma unroll
    for (int off = 32; off > 0; off >>= 1) v += __shfl_xor(v, off);
    __shared__ float ls[4];
    const int lane = (int)threadIdx.x & 63;
    const int wv   = (int)threadIdx.x >> 6;
    if (lane == 0) ls[wv] = v;
    __syncthreads();
    if (threadIdx.x == 0) out[0] = ls[0] + ls[1] + ls[2] + ls[3];
}

// ---------------------------------------------------------------------------
// Fallback (ws too small): contiguous y chunks, multi-pass; block sum +
// atomicAdd of the pre-divided contribution. Needs d_out zeroed first.
// ---------------------------------------------------------------------------
__global__ __launch_bounds__(TPB) void chamfer_atomic(
    const float* __restrict__ x, const float* __restrict__ y,
    const int* __restrict__ xlen, const int* __restrict__ ylen,
    float* __restrict__ out)
{
    __shared__ float4 sy[YCH];

    int bid = blockIdx.x;
    const int xc  = bid & (NXC - 1); bid >>= 2;
    const int n   = bid & (NB - 1);  bid >>= 3;
    const int dir = bid;

    const float* __restrict__ xs = dir ? y : x;
    const float* __restrict__ ys = dir ? x : y;
    const int yl = (dir ? xlen : ylen)[n];
    const int xl = (dir ? ylen : xlen)[n];

    float m0[XPT], m1[XPT], m2[XPT], a[XPT], emin[XPT];
    const int xi0 = xc * XCH + (int)threadIdx.x;
    const float* __restrict__ xb = xs + (size_t)n * PP * 3;
#pragma unroll
    for (int k = 0; k < XPT; ++k) {
        int xi = xi0 + k * TPB;
        float x0 = xb[xi * 3 + 0];
        float x1 = xb[xi * 3 + 1];
        float x2 = xb[xi * 3 + 2];
        m0[k] = -2.f * x0; m1[k] = -2.f * x1; m2[k] = -2.f * x2;
        a[k]  = fmaf(x0, x0, fmaf(x1, x1, x2 * x2));
        emin[k] = INFINITY;
    }

    for (int yc = 0; yc < NYC; ++yc) {
        const float* __restrict__ ybase = ys + ((size_t)n * PP + (size_t)yc * YCH) * 3;
        __syncthreads();
        if ((int)threadIdx.x < YCH) {
            int p = (int)threadIdx.x;
            float y0 = ybase[p * 3 + 0];
            float y1 = ybase[p * 3 + 1];
            float y2 = ybase[p * 3 + 2];
            sy[p] = make_float4(y0, y1, y2, fmaf(y0, y0, fmaf(y1, y1, y2 * y2)));
        }
        __syncthreads();
        int jend = yl - yc * YCH;
        if (jend > YCH) jend = YCH;
#pragma unroll 4
        for (int j = 0; j < jend; ++j) {
            float4 v = sy[j];
#pragma unroll
            for (int k = 0; k < XPT; ++k) {
                float e = fmaf(m0[k], v.x, fmaf(m1[k], v.y, fmaf(m2[k], v.z, v.w)));
                emin[k] = fminf(emin[k], e);
            }
        }
    }

    float sum = 0.f;
#pragma unroll
    for (int k = 0; k < XPT; ++k) {
        int xi = xi0 + k * TPB;
        if (xi < xl) sum += a[k] + emin[k];
    }
#pragma unroll
    for (int off = 32; off > 0; off >>= 1) sum += __shfl_xor(sum, off);
    __shared__ float ls[4];
    const int lane = (int)threadIdx.x & 63;
    const int wv   = (int)threadIdx.x >> 6;
    if (lane == 0) ls[wv] = sum;
    __syncthreads();
    if (threadIdx.x == 0) {
        float tot = ls[0] + ls[1] + ls[2] + ls[3];
        int d = xl > 1 ? xl : 1;
        atomicAdd(out, tot / (float)d / (float)NB);
    }
}

extern "C" void kernel_launch(void* const* d_in, const int* in_sizes, int n_in,
                              void* d_out, int out_size, void* d_ws, size_t ws_size,
                              hipStream_t stream) {
    const float* x  = (const float*)d_in[0];
    const float* y  = (const float*)d_in[1];
    const int* xl   = (const int*)d_in[2];
    const int* yl   = (const int*)d_in[3];
    float* out      = (float*)d_out;

    const size_t ws_floats = (size_t)2 * NB * NYC * PP;             // partial d2 table
    const size_t ws_need   = (ws_floats + NPART) * sizeof(float);   // + partials

    if (ws_size >= ws_need) {
        float* ws      = (float*)d_ws;
        float* partial = ws + ws_floats;
        nn_partial<<<GRIDA, TPB, 0, stream>>>(x, y, xl, yl, ws);
        reduce_cloud<<<NPART, 256, 0, stream>>>(ws, xl, yl, partial);
        final_sum<<<1, 256, 0, stream>>>(partial, out);
    } else {
        hipMemsetAsync(d_out, 0, sizeof(float), stream);
        const int gridF = 2 * NB * NXC;         // 64 blocks
        chamfer_atomic<<<gridF, TPB, 0, stream>>>(x, y, xl, yl, out);
    }
}